// Round 19
// baseline (77.768 us; speedup 1.0000x reference)
//
#include <hip/hip_runtime.h>
#include <math.h>

#define PI9 (2.0f * 3.14159265358979323846f / 9.0f)

typedef float f32x4 __attribute__((ext_vector_type(4)));
typedef unsigned short us8 __attribute__((ext_vector_type(8)));
typedef __bf16 bf16x8 __attribute__((ext_vector_type(8)));
typedef unsigned int u32x4 __attribute__((ext_vector_type(4)));

__device__ __forceinline__ float ssp_f(float x) {
  const float ax = fabsf(x);
  const float t = __expf(-ax);
  return fmaxf(x, 0.f) + __logf(1.f + t) - 0.69314718f;
}

__device__ __forceinline__ unsigned short f2bf(float f) {
  unsigned int u = __float_as_uint(f);
  unsigned int r = (u + 0x7FFFu + ((u >> 16) & 1u)) >> 16;
  return (unsigned short)r;
}

__device__ __forceinline__ float bfLO(unsigned int u) {
  return __uint_as_float(u << 16);
}
__device__ __forceinline__ float bfHI(unsigned int u) {
  return __uint_as_float(u & 0xffff0000u);
}

// ===========================================================================
// wconv: weight conversion + cnt zeroing.
// ===========================================================================
__global__ __launch_bounds__(256) void wconv_kernel(
    const float* __restrict__ W1, const float* __restrict__ W2,
    const float* __restrict__ W3, const float* __restrict__ a_w,
    const float* __restrict__ den, unsigned short* __restrict__ W1T,
    unsigned short* __restrict__ W2T, unsigned short* __restrict__ W3T,
    int* __restrict__ cnt, int N) {
  const int i = blockIdx.x * 256 + threadIdx.x;
  const float invden = 1.f / den[0];
  const float sc0 = a_w[0] * invden, sc1 = a_w[10] * invden, sc2 = a_w[22] * invden;
  const float rs8 = 0.35355339059327373f;
  if (i < N) cnt[i] = 0;
  if (i < 512) {
    const int col = i & 63, kk = i >> 6;
    W1T[col * 8 + kk] = f2bf(W1[kk * 64 + col] * rs8);
  } else if (i < 4608) {
    const int ii = i - 512;
    const int k = ii >> 6, j = ii & 63;
    W2T[j * 64 + ((((k >> 3) ^ (j & 7)) << 3)) + (k & 7)] = f2bf(W2[ii] * 0.125f);
  } else if (i < 7680) {
    const int ii = i - 4608;
    const int k = ii / 48, j = ii % 48;
    const int jm = j % 3;
    const float s = (jm == 0) ? sc0 : ((jm == 1) ? sc1 : sc2);
    W3T[j * 64 + ((((k >> 3) ^ (j & 7)) << 3)) + (k & 7)] = f2bf(W3[ii] * 0.125f * s);
  }
}

// ===========================================================================
// precompute_C body (9 blocks, one d-slice each) -> CT[d][p][q pad 12]
// ===========================================================================
__device__ void precompute_body(
    int d, unsigned char* smem,
    const float* __restrict__ Ux_re, const float* __restrict__ Ux_im,
    const float* __restrict__ Uf_re, const float* __restrict__ Uf_im,
    const float* __restrict__ Vo_re, const float* __restrict__ Vo_im,
    float* __restrict__ CT) {
  float* G = (float*)smem;                // 2*729 f
  float* TL = (float*)(smem + 5840);      // 729 f
  float* cs9 = (float*)(smem + 8768);
  float* sn9 = (float*)(smem + 8816);
  const int t0 = threadIdx.x;

  if (t0 < 9) {
    float s, c;
    __sincosf(PI9 * (float)t0, &s, &c);
    cs9[t0] = c; sn9[t0] = s;
  }
  __syncthreads();

  for (int t = t0; t < 1458; t += 256) {
    const int which = t / 729, idx = t % 729;
    const int p = idx / 81, ab = idx % 81, a = ab / 9, b = ab % 9;
    const float* Ure = which ? Uf_re : Ux_re;
    const float* Uim = which ? Uf_im : Ux_im;
    float g = 0.f;
#pragma unroll
    for (int v = 0; v < 3; ++v) {
      const int uc = v + 2;
      float hre = 0.f, him = 0.f;
#pragma unroll
      for (int ui = 0; ui < 5; ++ui) {
        const int u = (ui + 7) % 9;
        const float re = Ure[p * 25 + ui * 5 + uc];
        const float im = Uim[p * 25 + ui * 5 + uc];
        const int k = (u * a) % 9;
        const float c = cs9[k], s = sn9[k];
        hre += re * c - im * s;
        him += re * s + im * c;
      }
      hre *= (1.f / 9.f); him *= (1.f / 9.f);
      if (v == 0) {
        g += hre;
      } else {
        const int k = (v * b) % 9;
        g += 2.f * (hre * cs9[k] - him * sn9[k]);
      }
    }
    G[which * 729 + p * 81 + ab] = g * (1.f / 9.f);
  }
  __syncthreads();

  for (int t = t0; t < 729; t += 256) {
    const int ab = t / 9, dd = t % 9, a = ab / 9, b = ab % 9;
    float acc = 0.f;
    for (int u = 0; u < 9; ++u)
      for (int v = 0; v < 5; ++v) {
        const int k = (u * a + v * b) % 9;
        acc += Vo_re[u * 45 + v * 9 + dd] * cs9[k]
             + Vo_im[u * 45 + v * 9 + dd] * sn9[k];
      }
    TL[ab * 9 + dd] = acc;
  }
  __syncthreads();

  if (t0 < 108) {
    const int p = t0 / 12, q = t0 % 12;
    float acc = 0.f;
    if (q < 9) {
      for (int ab = 0; ab < 81; ++ab)
        acc += G[p * 81 + ab] * G[729 + q * 81 + ab] * TL[ab * 9 + d];
    }
    CT[(d * 9 + p) * 12 + q] = acc;
  }
}

// ===========================================================================
// MLP body (1 rep = 64 edges/block, 2500 blocks); stage1 via MFMA.
// ===========================================================================
__device__ void mlp_body(
    int mblk, unsigned char* smem, const float* __restrict__ win,
    const unsigned short* __restrict__ W1T,
    const unsigned short* __restrict__ W2T,
    const unsigned short* __restrict__ W3T,
    unsigned short* __restrict__ w48b) {
  unsigned short* H1 = (unsigned short*)smem + ((threadIdx.x >> 6) * 1024);
  unsigned short* H2 = (unsigned short*)(smem + 8192) + ((threadIdx.x >> 6) * 1024);
  const int t = threadIdx.x;
  const int w = t >> 6, l = t & 63;
  const int n16 = l & 15, g = l >> 4;
  const bool isg0 = (g == 0);

  const int e = mblk * 64 + w * 16 + n16;

  bf16x8 Aw;
#pragma unroll
  for (int j = 0; j < 8; ++j) Aw[j] = (__bf16)0.f;
  if (isg0) {
    const float4 A = *(const float4*)(win + (size_t)e * 8);
    const float4 B = *(const float4*)(win + (size_t)e * 8 + 4);
    Aw[0] = (__bf16)A.x; Aw[1] = (__bf16)A.y;
    Aw[2] = (__bf16)A.z; Aw[3] = (__bf16)A.w;
    Aw[4] = (__bf16)B.x; Aw[5] = (__bf16)B.y;
    Aw[6] = (__bf16)B.z; Aw[7] = (__bf16)B.w;
  }
#pragma unroll
  for (int nt = 0; nt < 4; ++nt) {
    const int col = nt * 16 + n16;
    us8 bz;
#pragma unroll
    for (int j = 0; j < 8; ++j) bz[j] = 0;
    const us8 bw = isg0 ? *(const us8*)&W1T[col * 8] : bz;
    f32x4 acc = {0.f, 0.f, 0.f, 0.f};
    acc = __builtin_amdgcn_mfma_f32_16x16x32_bf16(
        Aw, __builtin_bit_cast(bf16x8, bw), acc, 0, 0, 0);
#pragma unroll
    for (int r = 0; r < 4; ++r) {
      const int e2 = g * 4 + r;
      const int k2 = nt * 16 + n16;
      H1[e2 * 64 + ((((k2 >> 3) ^ (e2 & 7)) << 3)) + (k2 & 7)] =
          f2bf(ssp_f(acc[r]));
    }
  }
  __builtin_amdgcn_wave_barrier();

  {
    const us8 a0 = *(const us8*)&H1[n16 * 64 + ((g ^ (n16 & 7)) << 3)];
    const us8 a1 = *(const us8*)&H1[n16 * 64 + (((g + 4) ^ (n16 & 7)) << 3)];
    float hh[16];
#pragma unroll
    for (int nt = 0; nt < 4; ++nt) {
      const int j = nt * 16 + n16;
      const us8 b0 = *(const us8*)&W2T[j * 64 + ((g ^ (j & 7)) << 3)];
      const us8 b1 = *(const us8*)&W2T[j * 64 + (((g + 4) ^ (j & 7)) << 3)];
      f32x4 acc = {0.f, 0.f, 0.f, 0.f};
      acc = __builtin_amdgcn_mfma_f32_16x16x32_bf16(
          __builtin_bit_cast(bf16x8, a0), __builtin_bit_cast(bf16x8, b0), acc, 0, 0, 0);
      acc = __builtin_amdgcn_mfma_f32_16x16x32_bf16(
          __builtin_bit_cast(bf16x8, a1), __builtin_bit_cast(bf16x8, b1), acc, 0, 0, 0);
#pragma unroll
      for (int r = 0; r < 4; ++r) hh[nt * 4 + r] = ssp_f(acc[r]);
    }
#pragma unroll
    for (int nt = 0; nt < 4; ++nt)
#pragma unroll
      for (int r = 0; r < 4; ++r) {
        const int e2 = g * 4 + r;
        const int k2 = nt * 16 + n16;
        H2[e2 * 64 + ((((k2 >> 3) ^ (e2 & 7)) << 3)) + (k2 & 7)] =
            f2bf(hh[nt * 4 + r]);
      }
  }
  __builtin_amdgcn_wave_barrier();

  {
    const us8 c0 = *(const us8*)&H2[n16 * 64 + ((g ^ (n16 & 7)) << 3)];
    const us8 c1 = *(const us8*)&H2[n16 * 64 + (((g + 4) ^ (n16 & 7)) << 3)];
    const int ebase = mblk * 64 + w * 16 + g * 4;
#pragma unroll
    for (int nt = 0; nt < 3; ++nt) {
      const int o = nt * 16 + n16;
      const int om = o / 3, ol = o - om * 3;
      const us8 b0 = *(const us8*)&W3T[o * 64 + ((g ^ (o & 7)) << 3)];
      const us8 b1 = *(const us8*)&W3T[o * 64 + (((g + 4) ^ (o & 7)) << 3)];
      f32x4 acc = {0.f, 0.f, 0.f, 0.f};
      acc = __builtin_amdgcn_mfma_f32_16x16x32_bf16(
          __builtin_bit_cast(bf16x8, c0), __builtin_bit_cast(bf16x8, b0), acc, 0, 0, 0);
      acc = __builtin_amdgcn_mfma_f32_16x16x32_bf16(
          __builtin_bit_cast(bf16x8, c1), __builtin_bit_cast(bf16x8, b1), acc, 0, 0, 0);
#pragma unroll
      for (int r = 0; r < 4; ++r)
        w48b[(size_t)(ebase + r) * 64 + ol * 16 + om] = f2bf(acc[r]);
    }
  }
}

// ===========================================================================
// prep: [0,9) CT | [+nMlp) MLP | [+nScat) scatter | [+nXc) x->bf16 pad12
// ===========================================================================
__global__ __launch_bounds__(256) void prep_kernel(
    const float* __restrict__ win, const unsigned short* __restrict__ W1T,
    const unsigned short* __restrict__ W2T,
    const unsigned short* __restrict__ W3T,
    unsigned short* __restrict__ w48b,
    const int* __restrict__ dst, const int* __restrict__ src, int E,
    int* __restrict__ cnt, int2* __restrict__ slots2,
    const float* __restrict__ xsrc, int NR, unsigned short* __restrict__ xbf,
    const float* __restrict__ Ux_re, const float* __restrict__ Ux_im,
    const float* __restrict__ Uf_re, const float* __restrict__ Uf_im,
    const float* __restrict__ Vo_re, const float* __restrict__ Vo_im,
    float* __restrict__ CT, int nMlp, int nScat) {
  __shared__ __align__(16) unsigned char smem[16384];
  const int bid = blockIdx.x;
  if (bid < 9) {
    precompute_body(bid, smem, Ux_re, Ux_im, Uf_re, Uf_im, Vo_re, Vo_im, CT);
  } else if (bid < 9 + nMlp) {
    mlp_body(bid - 9, smem, win, W1T, W2T, W3T, w48b);
  } else if (bid < 9 + nMlp + nScat) {
    const int e = (bid - 9 - nMlp) * 256 + threadIdx.x;
    if (e < E) {
      const int d = dst[e];
      const int pos = atomicAdd(&cnt[d], 1);
      if (pos < 96) slots2[(size_t)d * 96 + pos] = make_int2(e, src[e]);
    }
  } else {
    const int r = (bid - 9 - nMlp - nScat) * 256 + threadIdx.x;
    if (r < NR) {
      const float* xp = xsrc + (size_t)r * 9;
      unsigned int u0 = (unsigned)f2bf(xp[0]) | ((unsigned)f2bf(xp[1]) << 16);
      unsigned int u1 = (unsigned)f2bf(xp[2]) | ((unsigned)f2bf(xp[3]) << 16);
      unsigned int u2 = (unsigned)f2bf(xp[4]) | ((unsigned)f2bf(xp[5]) << 16);
      unsigned int u3 = (unsigned)f2bf(xp[6]) | ((unsigned)f2bf(xp[7]) << 16);
      unsigned int u4 = (unsigned)f2bf(xp[8]);
      unsigned short* op = xbf + (size_t)r * 12;
      *(uint2*)op = make_uint2(u0, u1);
      *(uint2*)(op + 4) = make_uint2(u2, u3);
      *(uint2*)(op + 8) = make_uint2(u4, 0u);
    }
  }
}

// ===========================================================================
// Node kernel: wave-per-node, fused Me, branch-free message MFMA + 4-FMA
// epilogue.  2-deep load pipeline incl. LDS mdv; dual accumulators; next
// batch slot prefetch.
// ===========================================================================
__global__ __launch_bounds__(256) void node_kernel(
    const unsigned short* __restrict__ xbf, const float* __restrict__ filt,
    const int* __restrict__ cnt, const int2* __restrict__ slots2,
    const unsigned short* __restrict__ w48b, const float* __restrict__ CT,
    float* __restrict__ out, int N) {
  __shared__ __align__(16) unsigned short meL[4][2304];  // il*144 + d*16 + p
  const int t = threadIdx.x, w = t >> 6, l = t & 63;
  const int n16 = l & 15, g = l >> 4;
  const int Ld = (n16 == 0) ? 0 : ((n16 < 4) ? 1 : 2);
  const bool dok = n16 < 9;
  const int drow = dok ? n16 : 0;
  const bool isg0 = (g == 0), isg1 = (g == 1);
  const int n = blockIdx.x * 4 + w;
  if (n >= N) return;

  int dT0, pT0, dT1, pT1, dT2, pT2, dT3, pT3, dT4, pT4, dT5, pT5;
  bool ok0, ok1, ok2, ok3, ok4, ok5;
  bf16x8 Bme0, Bme1, Bme2, Bme3, Bme4, Bme5;
#define MKB(tt, Bv, dv, pv, okv)                                             \
  {                                                                          \
    const int col = tt * 16 + n16;                                           \
    okv = (col < 81);                                                        \
    dv = okv ? col / 9 : 0;                                                  \
    pv = okv ? col % 9 : 0;                                                  \
    bf16x8 bv;                                                               \
    _Pragma("unroll")                                                        \
    for (int j = 0; j < 8; ++j) bv[j] = (__bf16)0.f;                         \
    if (okv) {                                                               \
      const float* cp = CT + col * 12;                                       \
      if (g == 0) {                                                          \
        const float4 ca = *(const float4*)cp;                                \
        const float4 cb = *(const float4*)(cp + 4);                          \
        bv[0] = (__bf16)ca.x; bv[1] = (__bf16)ca.y;                          \
        bv[2] = (__bf16)ca.z; bv[3] = (__bf16)ca.w;                          \
        bv[4] = (__bf16)cb.x; bv[5] = (__bf16)cb.y;                          \
        bv[6] = (__bf16)cb.z; bv[7] = (__bf16)cb.w;                          \
      } else if (g == 1) {                                                   \
        bv[0] = (__bf16)cp[8];                                               \
      }                                                                      \
    }                                                                        \
    Bv = bv;                                                                 \
  }
  MKB(0, Bme0, dT0, pT0, ok0); MKB(1, Bme1, dT1, pT1, ok1);
  MKB(2, Bme2, dT2, pT2, ok2); MKB(3, Bme3, dT3, pT3, ok3);
  MKB(4, Bme4, dT4, pT4, ok4); MKB(5, Bme5, dT5, pT5, ok5);
#undef MKB

  int deg = cnt[n];
  if (deg > 96) deg = 96;
  const int2* sl2 = slots2 + (size_t)n * 96;
  unsigned short* mlw = &meL[w][0];

  f32x4 acc0 = {0.f, 0.f, 0.f, 0.f};
  f32x4 acc1 = {0.f, 0.f, 0.f, 0.f};

  const int nb = (deg + 15) >> 4;

  // preload batch-0 edge list
  int esx = 0, esy = 0;
  if (n16 < deg) {
    const int2 v = sl2[n16];
    esx = v.x; esy = v.y;
  }

  for (int b = 0; b < nb; ++b) {
    const int base = b * 16;
    const int degb = (deg - base < 16) ? (deg - base) : 16;

    bf16x8 Af;
#pragma unroll
    for (int j = 0; j < 8; ++j) Af[j] = (__bf16)0.f;
    if (n16 < degb) {
      const float* fp = filt + (size_t)esx * 9;
      if (g == 0) {
        const float4 fa = *(const float4*)fp;
        const float4 fb = *(const float4*)(fp + 4);
        Af[0] = (__bf16)fa.x; Af[1] = (__bf16)fa.y;
        Af[2] = (__bf16)fa.z; Af[3] = (__bf16)fa.w;
        Af[4] = (__bf16)fb.x; Af[5] = (__bf16)fb.y;
        Af[6] = (__bf16)fb.z; Af[7] = (__bf16)fb.w;
      } else if (g == 1) {
        Af[0] = (__bf16)fp[8];
      }
    }

#define MEMFMA(Bv, dv, pv, okv)                                              \
    {                                                                        \
      f32x4 a6 = {0.f, 0.f, 0.f, 0.f};                                       \
      a6 = __builtin_amdgcn_mfma_f32_16x16x32_bf16(Af, Bv, a6, 0, 0, 0);     \
      if (okv) {                                                             \
        _Pragma("unroll")                                                    \
        for (int r = 0; r < 4; ++r)                                          \
          mlw[(g * 4 + r) * 144 + dv * 16 + pv] = f2bf(a6[r]);               \
      }                                                                      \
    }
    MEMFMA(Bme0, dT0, pT0, ok0); MEMFMA(Bme1, dT1, pT1, ok1);
    MEMFMA(Bme2, dT2, pT2, ok2); MEMFMA(Bme3, dT3, pT3, ok3);
    MEMFMA(Bme4, dT4, pT4, ok4); MEMFMA(Bme5, dT5, pT5, ok5);
#undef MEMFMA

    // prefetch next batch edge list (overlaps Me latency + message loop)
    int esx_n = 0, esy_n = 0;
    if (b + 1 < nb && base + 16 + n16 < deg) {
      const int2 v = sl2[base + 16 + n16];
      esx_n = v.x; esy_n = v.y;
    }
    __builtin_amdgcn_wave_barrier();

    // ---- message loop: 2-wide unroll, A/B reg slots, dual accumulators
#define MSGLOAD(Q, QC, WV, MD, MD4, il_)                                     \
    {                                                                        \
      const int e_ = __builtin_amdgcn_readlane(esx, (il_));                  \
      const int s_ = __builtin_amdgcn_readlane(esy, (il_));                  \
      const unsigned short* xrp_ = xbf + (size_t)s_ * 192 + n16 * 12;        \
      Q = *(const u32x4*)xrp_;                                               \
      QC = *(const unsigned int*)(xrp_ + 8);                                 \
      WV = *(const uint2*)(w48b + (size_t)e_ * 64 + Ld * 16 + g * 4);        \
      const unsigned short* mr_ = mlw + (il_) * 144 + drow * 16;             \
      MD = *(const u32x4*)mr_;                                               \
      MD4 = (*(const unsigned int*)(mr_ + 8)) & 0xffffu;                     \
    }

#define MSGBODY(Q, QC, WV, MD, MD4, ACC)                                     \
    {                                                                        \
      u32x4 av;                                                              \
      av[0] = isg0 ? Q[0] : (isg1 ? QC : 0u);                                \
      av[1] = isg0 ? Q[1] : 0u;                                              \
      av[2] = isg0 ? Q[2] : 0u;                                              \
      av[3] = isg0 ? Q[3] : 0u;                                              \
      u32x4 bv;                                                              \
      bv[0] = isg0 ? MD[0] : (isg1 ? MD4 : 0u);                              \
      bv[1] = isg0 ? MD[1] : 0u;                                             \
      bv[2] = isg0 ? MD[2] : 0u;                                             \
      bv[3] = isg0 ? MD[3] : 0u;                                             \
      f32x4 c1 = {0.f, 0.f, 0.f, 0.f};                                       \
      c1 = __builtin_amdgcn_mfma_f32_16x16x32_bf16(                          \
          __builtin_bit_cast(bf16x8, av), __builtin_bit_cast(bf16x8, bv),    \
          c1, 0, 0, 0);                                                      \
      ACC[0] = fmaf(c1[0], bfLO(WV.x), ACC[0]);                              \
      ACC[1] = fmaf(c1[1], bfHI(WV.x), ACC[1]);                              \
      ACC[2] = fmaf(c1[2], bfLO(WV.y), ACC[2]);                              \
      ACC[3] = fmaf(c1[3], bfHI(WV.y), ACC[3]);                              \
    }

    u32x4 qA, qB, mdA, mdB;
    unsigned int qcA, qcB, md4A, md4B;
    uint2 wvA, wvB;
    MSGLOAD(qA, qcA, wvA, mdA, md4A, 0);
    if (degb > 1) MSGLOAD(qB, qcB, wvB, mdB, md4B, 1);

    int il = 0;
#pragma unroll 1
    for (; il + 2 <= degb; il += 2) {
      const u32x4 q0 = qA, m0 = mdA;
      const unsigned int qc0 = qcA, m40 = md4A;
      const uint2 wv0 = wvA;
      const u32x4 q1 = qB, m1 = mdB;
      const unsigned int qc1 = qcB, m41 = md4B;
      const uint2 wv1 = wvB;
      if (il + 2 < degb) MSGLOAD(qA, qcA, wvA, mdA, md4A, il + 2);
      if (il + 3 < degb) MSGLOAD(qB, qcB, wvB, mdB, md4B, il + 3);
      MSGBODY(q0, qc0, wv0, m0, m40, acc0);
      MSGBODY(q1, qc1, wv1, m1, m41, acc1);
    }
    if (il < degb) MSGBODY(qA, qcA, wvA, mdA, md4A, acc0);
#undef MSGLOAD
#undef MSGBODY
    __builtin_amdgcn_wave_barrier();

    esx = esx_n; esy = esy_n;
  }

  if (dok) {
    float* op = out + (size_t)n * 144 + (g * 4) * 9 + n16;
    op[0]  = acc0[0] + acc1[0];
    op[9]  = acc0[1] + acc1[1];
    op[18] = acc0[2] + acc1[2];
    op[27] = acc0[3] + acc1[3];
  }
}

// ---------------------------------------------------------------------------
extern "C" void kernel_launch(void* const* d_in, const int* in_sizes, int n_in,
                              void* d_out, int out_size, void* d_ws, size_t ws_size,
                              hipStream_t stream) {
  const float* x      = (const float*)d_in[0];
  const float* filt   = (const float*)d_in[1];
  const float* win    = (const float*)d_in[2];
  const int*   eidx   = (const int*)d_in[3];
  const float* Ux_re  = (const float*)d_in[4];
  const float* Ux_im  = (const float*)d_in[5];
  const float* Uf_re  = (const float*)d_in[6];
  const float* Uf_im  = (const float*)d_in[7];
  const float* Vo_re  = (const float*)d_in[8];
  const float* Vo_im  = (const float*)d_in[9];
  const float* W1     = (const float*)d_in[10];
  const float* W2     = (const float*)d_in[11];
  const float* W3     = (const float*)d_in[12];
  const float* a_w    = (const float*)d_in[13];
  const float* den    = (const float*)d_in[14];
  float* out = (float*)d_out;

  const int N = in_sizes[0] / 144;          // 10000
  const int E = in_sizes[3] / 2;            // 160000
  const int NR = N * 16;                    // x rows (node, m)
  const int* dst = eidx;
  const int* src = eidx + E;

  char* wsb = (char*)d_ws;
  const size_t off_cnt  = 8192;
  const size_t off_slot = off_cnt + 40960;
  const size_t off_w48  = off_slot + (size_t)N * 96 * 8;
  const size_t off_xbf  = off_w48 + (size_t)E * 64 * 2;
  const size_t off_w1t  = off_xbf + (size_t)NR * 12 * 2;
  const size_t off_w2t  = off_w1t + 512 * 2;
  const size_t off_w3t  = off_w2t + 4096 * 2;

  float*          CT    = (float*)wsb;
  int*            cnt   = (int*)(wsb + off_cnt);
  int2*           slot2 = (int2*)(wsb + off_slot);
  unsigned short* w48b  = (unsigned short*)(wsb + off_w48);  // E*64 shorts
  unsigned short* xbf   = (unsigned short*)(wsb + off_xbf);  // NR*12 shorts
  unsigned short* W1T   = (unsigned short*)(wsb + off_w1t);
  unsigned short* W2T   = (unsigned short*)(wsb + off_w2t);
  unsigned short* W3T   = (unsigned short*)(wsb + off_w3t);

  const int nMlp  = E / 64;                 // 2500
  const int nScat = (E + 255) / 256;        // 625
  const int nXc   = (NR + 255) / 256;       // 625

  wconv_kernel<<<(N + 255) / 256, 256, 0, stream>>>(
      W1, W2, W3, a_w, den, W1T, W2T, W3T, cnt, N);
  prep_kernel<<<9 + nMlp + nScat + nXc, 256, 0, stream>>>(
      win, W1T, W2T, W3T, w48b,
      dst, src, E, cnt, slot2,
      x, NR, xbf,
      Ux_re, Ux_im, Uf_re, Uf_im, Vo_re, Vo_im, CT, nMlp, nScat);
  node_kernel<<<(N + 3) / 4, 256, 0, stream>>>(
      xbf, filt, cnt, slot2, w48b, CT, out, N);
}

// Round 20
// 73.981 us; speedup vs baseline: 1.0512x; 1.0512x over previous
//
#include <hip/hip_runtime.h>
#include <math.h>

#define PI9 (2.0f * 3.14159265358979323846f / 9.0f)

typedef float f32x4 __attribute__((ext_vector_type(4)));
typedef unsigned short us8 __attribute__((ext_vector_type(8)));
typedef __bf16 bf16x8 __attribute__((ext_vector_type(8)));
typedef unsigned int u32x4 __attribute__((ext_vector_type(4)));

__device__ __forceinline__ float ssp_f(float x) {
  const float ax = fabsf(x);
  const float t = __expf(-ax);
  return fmaxf(x, 0.f) + __logf(1.f + t) - 0.69314718f;
}

__device__ __forceinline__ unsigned short f2bf(float f) {
  unsigned int u = __float_as_uint(f);
  unsigned int r = (u + 0x7FFFu + ((u >> 16) & 1u)) >> 16;
  return (unsigned short)r;
}

__device__ __forceinline__ float bfLO(unsigned int u) {
  return __uint_as_float(u << 16);
}
__device__ __forceinline__ float bfHI(unsigned int u) {
  return __uint_as_float(u & 0xffff0000u);
}

// ===========================================================================
// wconv: weight conversion + cnt zeroing.
// ===========================================================================
__global__ __launch_bounds__(256) void wconv_kernel(
    const float* __restrict__ W1, const float* __restrict__ W2,
    const float* __restrict__ W3, const float* __restrict__ a_w,
    const float* __restrict__ den, unsigned short* __restrict__ W1T,
    unsigned short* __restrict__ W2T, unsigned short* __restrict__ W3T,
    int* __restrict__ cnt, int N) {
  const int i = blockIdx.x * 256 + threadIdx.x;
  const float invden = 1.f / den[0];
  const float sc0 = a_w[0] * invden, sc1 = a_w[10] * invden, sc2 = a_w[22] * invden;
  const float rs8 = 0.35355339059327373f;
  if (i < N) cnt[i] = 0;
  if (i < 512) {
    const int col = i & 63, kk = i >> 6;
    W1T[col * 8 + kk] = f2bf(W1[kk * 64 + col] * rs8);
  } else if (i < 4608) {
    const int ii = i - 512;
    const int k = ii >> 6, j = ii & 63;
    W2T[j * 64 + ((((k >> 3) ^ (j & 7)) << 3)) + (k & 7)] = f2bf(W2[ii] * 0.125f);
  } else if (i < 7680) {
    const int ii = i - 4608;
    const int k = ii / 48, j = ii % 48;
    const int jm = j % 3;
    const float s = (jm == 0) ? sc0 : ((jm == 1) ? sc1 : sc2);
    W3T[j * 64 + ((((k >> 3) ^ (j & 7)) << 3)) + (k & 7)] = f2bf(W3[ii] * 0.125f * s);
  }
}

// ===========================================================================
// precompute_C body (9 blocks, one d-slice each) -> CT[d][p][q pad 12]
// ===========================================================================
__device__ void precompute_body(
    int d, unsigned char* smem,
    const float* __restrict__ Ux_re, const float* __restrict__ Ux_im,
    const float* __restrict__ Uf_re, const float* __restrict__ Uf_im,
    const float* __restrict__ Vo_re, const float* __restrict__ Vo_im,
    float* __restrict__ CT) {
  float* G = (float*)smem;                // 2*729 f
  float* TL = (float*)(smem + 5840);      // 729 f
  float* cs9 = (float*)(smem + 8768);
  float* sn9 = (float*)(smem + 8816);
  const int t0 = threadIdx.x;

  if (t0 < 9) {
    float s, c;
    __sincosf(PI9 * (float)t0, &s, &c);
    cs9[t0] = c; sn9[t0] = s;
  }
  __syncthreads();

  for (int t = t0; t < 1458; t += 256) {
    const int which = t / 729, idx = t % 729;
    const int p = idx / 81, ab = idx % 81, a = ab / 9, b = ab % 9;
    const float* Ure = which ? Uf_re : Ux_re;
    const float* Uim = which ? Uf_im : Ux_im;
    float g = 0.f;
#pragma unroll
    for (int v = 0; v < 3; ++v) {
      const int uc = v + 2;
      float hre = 0.f, him = 0.f;
#pragma unroll
      for (int ui = 0; ui < 5; ++ui) {
        const int u = (ui + 7) % 9;
        const float re = Ure[p * 25 + ui * 5 + uc];
        const float im = Uim[p * 25 + ui * 5 + uc];
        const int k = (u * a) % 9;
        const float c = cs9[k], s = sn9[k];
        hre += re * c - im * s;
        him += re * s + im * c;
      }
      hre *= (1.f / 9.f); him *= (1.f / 9.f);
      if (v == 0) {
        g += hre;
      } else {
        const int k = (v * b) % 9;
        g += 2.f * (hre * cs9[k] - him * sn9[k]);
      }
    }
    G[which * 729 + p * 81 + ab] = g * (1.f / 9.f);
  }
  __syncthreads();

  for (int t = t0; t < 729; t += 256) {
    const int ab = t / 9, dd = t % 9, a = ab / 9, b = ab % 9;
    float acc = 0.f;
    for (int u = 0; u < 9; ++u)
      for (int v = 0; v < 5; ++v) {
        const int k = (u * a + v * b) % 9;
        acc += Vo_re[u * 45 + v * 9 + dd] * cs9[k]
             + Vo_im[u * 45 + v * 9 + dd] * sn9[k];
      }
    TL[ab * 9 + dd] = acc;
  }
  __syncthreads();

  if (t0 < 108) {
    const int p = t0 / 12, q = t0 % 12;
    float acc = 0.f;
    if (q < 9) {
      for (int ab = 0; ab < 81; ++ab)
        acc += G[p * 81 + ab] * G[729 + q * 81 + ab] * TL[ab * 9 + d];
    }
    CT[(d * 9 + p) * 12 + q] = acc;
  }
}

// ===========================================================================
// MLP body (2 reps = 128 edges/block); stage1 via MFMA; weights from global.
// ===========================================================================
__device__ void mlp_body(
    int mblk, unsigned char* smem, const float* __restrict__ win,
    const unsigned short* __restrict__ W1T,
    const unsigned short* __restrict__ W2T,
    const unsigned short* __restrict__ W3T,
    unsigned short* __restrict__ w48b) {
  unsigned short* H1 = (unsigned short*)smem + ((threadIdx.x >> 6) * 1024);
  unsigned short* H2 = (unsigned short*)(smem + 8192) + ((threadIdx.x >> 6) * 1024);
  const int t = threadIdx.x;
  const int w = t >> 6, l = t & 63;
  const int n16 = l & 15, g = l >> 4;
  const bool isg0 = (g == 0);

#pragma unroll 1
  for (int rep = 0; rep < 2; ++rep) {
    const int e = mblk * 128 + rep * 64 + w * 16 + n16;

    bf16x8 Aw;
#pragma unroll
    for (int j = 0; j < 8; ++j) Aw[j] = (__bf16)0.f;
    if (isg0) {
      const float4 A = *(const float4*)(win + (size_t)e * 8);
      const float4 B = *(const float4*)(win + (size_t)e * 8 + 4);
      Aw[0] = (__bf16)A.x; Aw[1] = (__bf16)A.y;
      Aw[2] = (__bf16)A.z; Aw[3] = (__bf16)A.w;
      Aw[4] = (__bf16)B.x; Aw[5] = (__bf16)B.y;
      Aw[6] = (__bf16)B.z; Aw[7] = (__bf16)B.w;
    }
#pragma unroll
    for (int nt = 0; nt < 4; ++nt) {
      const int col = nt * 16 + n16;
      us8 bz;
#pragma unroll
      for (int j = 0; j < 8; ++j) bz[j] = 0;
      const us8 bw = isg0 ? *(const us8*)&W1T[col * 8] : bz;
      f32x4 acc = {0.f, 0.f, 0.f, 0.f};
      acc = __builtin_amdgcn_mfma_f32_16x16x32_bf16(
          Aw, __builtin_bit_cast(bf16x8, bw), acc, 0, 0, 0);
#pragma unroll
      for (int r = 0; r < 4; ++r) {
        const int e2 = g * 4 + r;
        const int k2 = nt * 16 + n16;
        H1[e2 * 64 + ((((k2 >> 3) ^ (e2 & 7)) << 3)) + (k2 & 7)] =
            f2bf(ssp_f(acc[r]));
      }
    }
    __builtin_amdgcn_wave_barrier();

    {
      const us8 a0 = *(const us8*)&H1[n16 * 64 + ((g ^ (n16 & 7)) << 3)];
      const us8 a1 = *(const us8*)&H1[n16 * 64 + (((g + 4) ^ (n16 & 7)) << 3)];
      float hh[16];
#pragma unroll
      for (int nt = 0; nt < 4; ++nt) {
        const int j = nt * 16 + n16;
        const us8 b0 = *(const us8*)&W2T[j * 64 + ((g ^ (j & 7)) << 3)];
        const us8 b1 = *(const us8*)&W2T[j * 64 + (((g + 4) ^ (j & 7)) << 3)];
        f32x4 acc = {0.f, 0.f, 0.f, 0.f};
        acc = __builtin_amdgcn_mfma_f32_16x16x32_bf16(
            __builtin_bit_cast(bf16x8, a0), __builtin_bit_cast(bf16x8, b0), acc, 0, 0, 0);
        acc = __builtin_amdgcn_mfma_f32_16x16x32_bf16(
            __builtin_bit_cast(bf16x8, a1), __builtin_bit_cast(bf16x8, b1), acc, 0, 0, 0);
#pragma unroll
        for (int r = 0; r < 4; ++r) hh[nt * 4 + r] = ssp_f(acc[r]);
      }
#pragma unroll
      for (int nt = 0; nt < 4; ++nt)
#pragma unroll
        for (int r = 0; r < 4; ++r) {
          const int e2 = g * 4 + r;
          const int k2 = nt * 16 + n16;
          H2[e2 * 64 + ((((k2 >> 3) ^ (e2 & 7)) << 3)) + (k2 & 7)] =
              f2bf(hh[nt * 4 + r]);
        }
    }
    __builtin_amdgcn_wave_barrier();

    {
      const us8 c0 = *(const us8*)&H2[n16 * 64 + ((g ^ (n16 & 7)) << 3)];
      const us8 c1 = *(const us8*)&H2[n16 * 64 + (((g + 4) ^ (n16 & 7)) << 3)];
      const int ebase = mblk * 128 + rep * 64 + w * 16 + g * 4;
#pragma unroll
      for (int nt = 0; nt < 3; ++nt) {
        const int o = nt * 16 + n16;
        const int om = o / 3, ol = o - om * 3;
        const us8 b0 = *(const us8*)&W3T[o * 64 + ((g ^ (o & 7)) << 3)];
        const us8 b1 = *(const us8*)&W3T[o * 64 + (((g + 4) ^ (o & 7)) << 3)];
        f32x4 acc = {0.f, 0.f, 0.f, 0.f};
        acc = __builtin_amdgcn_mfma_f32_16x16x32_bf16(
            __builtin_bit_cast(bf16x8, c0), __builtin_bit_cast(bf16x8, b0), acc, 0, 0, 0);
        acc = __builtin_amdgcn_mfma_f32_16x16x32_bf16(
            __builtin_bit_cast(bf16x8, c1), __builtin_bit_cast(bf16x8, b1), acc, 0, 0, 0);
#pragma unroll
        for (int r = 0; r < 4; ++r)
          w48b[(size_t)(ebase + r) * 64 + ol * 16 + om] = f2bf(acc[r]);
      }
    }
    __builtin_amdgcn_wave_barrier();
  }
}

// ===========================================================================
// prep: [0,9) CT | [+nMlp) MLP | [+nScat) scatter | [+nXc) x->bf16 pad12
// All roles independent; latency-bound roles co-schedule under MLP MFMA.
// ===========================================================================
__global__ __launch_bounds__(256) void prep_kernel(
    const float* __restrict__ win, const unsigned short* __restrict__ W1T,
    const unsigned short* __restrict__ W2T,
    const unsigned short* __restrict__ W3T,
    unsigned short* __restrict__ w48b,
    const int* __restrict__ dst, const int* __restrict__ src, int E,
    int* __restrict__ cnt, int2* __restrict__ slots2,
    const float* __restrict__ xsrc, int NR, unsigned short* __restrict__ xbf,
    const float* __restrict__ Ux_re, const float* __restrict__ Ux_im,
    const float* __restrict__ Uf_re, const float* __restrict__ Uf_im,
    const float* __restrict__ Vo_re, const float* __restrict__ Vo_im,
    float* __restrict__ CT, int nMlp, int nScat) {
  __shared__ __align__(16) unsigned char smem[16384];
  const int bid = blockIdx.x;
  if (bid < 9) {
    precompute_body(bid, smem, Ux_re, Ux_im, Uf_re, Uf_im, Vo_re, Vo_im, CT);
  } else if (bid < 9 + nMlp) {
    mlp_body(bid - 9, smem, win, W1T, W2T, W3T, w48b);
  } else if (bid < 9 + nMlp + nScat) {
    const int e = (bid - 9 - nMlp) * 256 + threadIdx.x;
    if (e < E) {
      const int d = dst[e];
      const int pos = atomicAdd(&cnt[d], 1);
      if (pos < 96) slots2[(size_t)d * 96 + pos] = make_int2(e, src[e]);
    }
  } else {
    const int r = (bid - 9 - nMlp - nScat) * 256 + threadIdx.x;
    if (r < NR) {
      const float* xp = xsrc + (size_t)r * 9;
      unsigned int u0 = (unsigned)f2bf(xp[0]) | ((unsigned)f2bf(xp[1]) << 16);
      unsigned int u1 = (unsigned)f2bf(xp[2]) | ((unsigned)f2bf(xp[3]) << 16);
      unsigned int u2 = (unsigned)f2bf(xp[4]) | ((unsigned)f2bf(xp[5]) << 16);
      unsigned int u3 = (unsigned)f2bf(xp[6]) | ((unsigned)f2bf(xp[7]) << 16);
      unsigned int u4 = (unsigned)f2bf(xp[8]);
      unsigned short* op = xbf + (size_t)r * 12;
      *(uint2*)op = make_uint2(u0, u1);
      *(uint2*)(op + 4) = make_uint2(u2, u3);
      *(uint2*)(op + 8) = make_uint2(u4, 0u);
    }
  }
}

// ===========================================================================
// Node kernel: wave-per-node, fused Me, branch-free message MFMA + 4-FMA
// epilogue.  2-deep (A/B) pipeline on xbf/w48 loads in message loop.
// ===========================================================================
__global__ __launch_bounds__(256) void node_kernel(
    const unsigned short* __restrict__ xbf, const float* __restrict__ filt,
    const int* __restrict__ cnt, const int2* __restrict__ slots2,
    const unsigned short* __restrict__ w48b, const float* __restrict__ CT,
    float* __restrict__ out, int N) {
  __shared__ __align__(16) unsigned short meL[4][2304];  // il*144 + d*16 + p
  const int t = threadIdx.x, w = t >> 6, l = t & 63;
  const int n16 = l & 15, g = l >> 4;
  const int Ld = (n16 == 0) ? 0 : ((n16 < 4) ? 1 : 2);
  const bool dok = n16 < 9;
  const int drow = dok ? n16 : 0;
  const bool isg0 = (g == 0), isg1 = (g == 1);
  const int n = blockIdx.x * 4 + w;
  if (n >= N) return;

  int dT0, pT0, dT1, pT1, dT2, pT2, dT3, pT3, dT4, pT4, dT5, pT5;
  bool ok0, ok1, ok2, ok3, ok4, ok5;
  bf16x8 Bme0, Bme1, Bme2, Bme3, Bme4, Bme5;
#define MKB(tt, Bv, dv, pv, okv)                                             \
  {                                                                          \
    const int col = tt * 16 + n16;                                           \
    okv = (col < 81);                                                        \
    dv = okv ? col / 9 : 0;                                                  \
    pv = okv ? col % 9 : 0;                                                  \
    bf16x8 bv;                                                               \
    _Pragma("unroll")                                                        \
    for (int j = 0; j < 8; ++j) bv[j] = (__bf16)0.f;                         \
    if (okv) {                                                               \
      const float* cp = CT + col * 12;                                       \
      if (g == 0) {                                                          \
        const float4 ca = *(const float4*)cp;                                \
        const float4 cb = *(const float4*)(cp + 4);                          \
        bv[0] = (__bf16)ca.x; bv[1] = (__bf16)ca.y;                          \
        bv[2] = (__bf16)ca.z; bv[3] = (__bf16)ca.w;                          \
        bv[4] = (__bf16)cb.x; bv[5] = (__bf16)cb.y;                          \
        bv[6] = (__bf16)cb.z; bv[7] = (__bf16)cb.w;                          \
      } else if (g == 1) {                                                   \
        bv[0] = (__bf16)cp[8];                                               \
      }                                                                      \
    }                                                                        \
    Bv = bv;                                                                 \
  }
  MKB(0, Bme0, dT0, pT0, ok0); MKB(1, Bme1, dT1, pT1, ok1);
  MKB(2, Bme2, dT2, pT2, ok2); MKB(3, Bme3, dT3, pT3, ok3);
  MKB(4, Bme4, dT4, pT4, ok4); MKB(5, Bme5, dT5, pT5, ok5);
#undef MKB

  int deg = cnt[n];
  if (deg > 96) deg = 96;
  const int2* sl2 = slots2 + (size_t)n * 96;
  unsigned short* mlw = &meL[w][0];

  f32x4 accm = {0.f, 0.f, 0.f, 0.f};

  const int nb = (deg + 15) >> 4;
  for (int b = 0; b < nb; ++b) {
    const int base = b * 16;
    const int degb = (deg - base < 16) ? (deg - base) : 16;

    int esx = 0, esy = 0;
    if (n16 < degb) {
      const int2 v = sl2[base + n16];
      esx = v.x; esy = v.y;
    }
    bf16x8 Af;
#pragma unroll
    for (int j = 0; j < 8; ++j) Af[j] = (__bf16)0.f;
    if (n16 < degb) {
      const float* fp = filt + (size_t)esx * 9;
      if (g == 0) {
        const float4 fa = *(const float4*)fp;
        const float4 fb = *(const float4*)(fp + 4);
        Af[0] = (__bf16)fa.x; Af[1] = (__bf16)fa.y;
        Af[2] = (__bf16)fa.z; Af[3] = (__bf16)fa.w;
        Af[4] = (__bf16)fb.x; Af[5] = (__bf16)fb.y;
        Af[6] = (__bf16)fb.z; Af[7] = (__bf16)fb.w;
      } else if (g == 1) {
        Af[0] = (__bf16)fp[8];
      }
    }

#define MEMFMA(Bv, dv, pv, okv)                                              \
    {                                                                        \
      f32x4 a6 = {0.f, 0.f, 0.f, 0.f};                                       \
      a6 = __builtin_amdgcn_mfma_f32_16x16x32_bf16(Af, Bv, a6, 0, 0, 0);     \
      if (okv) {                                                             \
        _Pragma("unroll")                                                    \
        for (int r = 0; r < 4; ++r)                                          \
          mlw[(g * 4 + r) * 144 + dv * 16 + pv] = f2bf(a6[r]);               \
      }                                                                      \
    }
    MEMFMA(Bme0, dT0, pT0, ok0); MEMFMA(Bme1, dT1, pT1, ok1);
    MEMFMA(Bme2, dT2, pT2, ok2); MEMFMA(Bme3, dT3, pT3, ok3);
    MEMFMA(Bme4, dT4, pT4, ok4); MEMFMA(Bme5, dT5, pT5, ok5);
#undef MEMFMA
    __builtin_amdgcn_wave_barrier();

    // ---- message loop with 2-deep A/B load pipeline
#define MSGLOAD(Q, QC, WV, il_)                                              \
    {                                                                        \
      const int e_ = __builtin_amdgcn_readlane(esx, (il_));                  \
      const int s_ = __builtin_amdgcn_readlane(esy, (il_));                  \
      const unsigned short* xrp_ = xbf + (size_t)s_ * 192 + n16 * 12;        \
      Q = *(const u32x4*)xrp_;                                               \
      QC = *(const unsigned int*)(xrp_ + 8);                                 \
      WV = *(const uint2*)(w48b + (size_t)e_ * 64 + Ld * 16 + g * 4);        \
    }

    u32x4 qA, qB;
    unsigned int qcA, qcB;
    uint2 wvA, wvB;
    MSGLOAD(qA, qcA, wvA, 0);
    if (degb > 1) MSGLOAD(qB, qcB, wvB, 1);

#pragma unroll 1
    for (int il = 0; il < degb; ++il) {
      const u32x4 q = qA;
      const unsigned int qc = qcA;
      const uint2 wv = wvA;
      // rotate pipeline
      qA = qB; qcA = qcB; wvA = wvB;
      if (il + 2 < degb) MSGLOAD(qB, qcB, wvB, il + 2);

      const unsigned short* mr = mlw + il * 144 + drow * 16;
      const u32x4 mdv = *(const u32x4*)mr;
      const unsigned int md4 = (*(const unsigned int*)(mr + 8)) & 0xffffu;

      u32x4 av;
      av[0] = isg0 ? q[0] : (isg1 ? qc : 0u);
      av[1] = isg0 ? q[1] : 0u;
      av[2] = isg0 ? q[2] : 0u;
      av[3] = isg0 ? q[3] : 0u;
      u32x4 bv;
      bv[0] = isg0 ? mdv[0] : (isg1 ? md4 : 0u);
      bv[1] = isg0 ? mdv[1] : 0u;
      bv[2] = isg0 ? mdv[2] : 0u;
      bv[3] = isg0 ? mdv[3] : 0u;

      f32x4 c1 = {0.f, 0.f, 0.f, 0.f};
      c1 = __builtin_amdgcn_mfma_f32_16x16x32_bf16(
          __builtin_bit_cast(bf16x8, av), __builtin_bit_cast(bf16x8, bv),
          c1, 0, 0, 0);
      accm[0] = fmaf(c1[0], bfLO(wv.x), accm[0]);
      accm[1] = fmaf(c1[1], bfHI(wv.x), accm[1]);
      accm[2] = fmaf(c1[2], bfLO(wv.y), accm[2]);
      accm[3] = fmaf(c1[3], bfHI(wv.y), accm[3]);
    }
#undef MSGLOAD
    __builtin_amdgcn_wave_barrier();
  }

  if (dok) {
    float* op = out + (size_t)n * 144 + (g * 4) * 9 + n16;
    op[0]  = accm[0];
    op[9]  = accm[1];
    op[18] = accm[2];
    op[27] = accm[3];
  }
}

// ---------------------------------------------------------------------------
extern "C" void kernel_launch(void* const* d_in, const int* in_sizes, int n_in,
                              void* d_out, int out_size, void* d_ws, size_t ws_size,
                              hipStream_t stream) {
  const float* x      = (const float*)d_in[0];
  const float* filt   = (const float*)d_in[1];
  const float* win    = (const float*)d_in[2];
  const int*   eidx   = (const int*)d_in[3];
  const float* Ux_re  = (const float*)d_in[4];
  const float* Ux_im  = (const float*)d_in[5];
  const float* Uf_re  = (const float*)d_in[6];
  const float* Uf_im  = (const float*)d_in[7];
  const float* Vo_re  = (const float*)d_in[8];
  const float* Vo_im  = (const float*)d_in[9];
  const float* W1     = (const float*)d_in[10];
  const float* W2     = (const float*)d_in[11];
  const float* W3     = (const float*)d_in[12];
  const float* a_w    = (const float*)d_in[13];
  const float* den    = (const float*)d_in[14];
  float* out = (float*)d_out;

  const int N = in_sizes[0] / 144;          // 10000
  const int E = in_sizes[3] / 2;            // 160000
  const int NR = N * 16;                    // x rows (node, m)
  const int* dst = eidx;
  const int* src = eidx + E;

  char* wsb = (char*)d_ws;
  const size_t off_cnt  = 8192;
  const size_t off_slot = off_cnt + 40960;
  const size_t off_w48  = off_slot + (size_t)N * 96 * 8;
  const size_t off_xbf  = off_w48 + (size_t)E * 64 * 2;
  const size_t off_w1t  = off_xbf + (size_t)NR * 12 * 2;
  const size_t off_w2t  = off_w1t + 512 * 2;
  const size_t off_w3t  = off_w2t + 4096 * 2;

  float*          CT    = (float*)wsb;
  int*            cnt   = (int*)(wsb + off_cnt);
  int2*           slot2 = (int2*)(wsb + off_slot);
  unsigned short* w48b  = (unsigned short*)(wsb + off_w48);  // E*64 shorts
  unsigned short* xbf   = (unsigned short*)(wsb + off_xbf);  // NR*12 shorts
  unsigned short* W1T   = (unsigned short*)(wsb + off_w1t);
  unsigned short* W2T   = (unsigned short*)(wsb + off_w2t);
  unsigned short* W3T   = (unsigned short*)(wsb + off_w3t);

  const int nMlp  = E / 128;                // 1250
  const int nScat = (E + 255) / 256;        // 625
  const int nXc   = (NR + 255) / 256;       // 625

  wconv_kernel<<<(N + 255) / 256, 256, 0, stream>>>(
      W1, W2, W3, a_w, den, W1T, W2T, W3T, cnt, N);
  prep_kernel<<<9 + nMlp + nScat + nXc, 256, 0, stream>>>(
      win, W1T, W2T, W3T, w48b,
      dst, src, E, cnt, slot2,
      x, NR, xbf,
      Ux_re, Ux_im, Uf_re, Uf_im, Vo_re, Vo_im, CT, nMlp, nScat);
  node_kernel<<<(N + 3) / 4, 256, 0, stream>>>(
      xbf, filt, cnt, slot2, w48b, CT, out, N);
}

// Round 21
// 72.067 us; speedup vs baseline: 1.0791x; 1.0266x over previous
//
#include <hip/hip_runtime.h>
#include <math.h>

#define PI9 (2.0f * 3.14159265358979323846f / 9.0f)

typedef float f32x4 __attribute__((ext_vector_type(4)));
typedef unsigned short us8 __attribute__((ext_vector_type(8)));
typedef __bf16 bf16x8 __attribute__((ext_vector_type(8)));
typedef unsigned int u32x4 __attribute__((ext_vector_type(4)));

__device__ __forceinline__ float ssp_f(float x) {
  const float ax = fabsf(x);
  const float t = __expf(-ax);
  return fmaxf(x, 0.f) + __logf(1.f + t) - 0.69314718f;
}

__device__ __forceinline__ unsigned short f2bf(float f) {
  unsigned int u = __float_as_uint(f);
  unsigned int r = (u + 0x7FFFu + ((u >> 16) & 1u)) >> 16;
  return (unsigned short)r;
}

__device__ __forceinline__ float bfLO(unsigned int u) {
  return __uint_as_float(u << 16);
}
__device__ __forceinline__ float bfHI(unsigned int u) {
  return __uint_as_float(u & 0xffff0000u);
}

// ===========================================================================
// wconv: weight conversion + cnt zeroing.
// ===========================================================================
__global__ __launch_bounds__(256) void wconv_kernel(
    const float* __restrict__ W1, const float* __restrict__ W2,
    const float* __restrict__ W3, const float* __restrict__ a_w,
    const float* __restrict__ den, unsigned short* __restrict__ W1T,
    unsigned short* __restrict__ W2T, unsigned short* __restrict__ W3T,
    int* __restrict__ cnt, int N) {
  const int i = blockIdx.x * 256 + threadIdx.x;
  const float invden = 1.f / den[0];
  const float sc0 = a_w[0] * invden, sc1 = a_w[10] * invden, sc2 = a_w[22] * invden;
  const float rs8 = 0.35355339059327373f;
  if (i < N) cnt[i] = 0;
  if (i < 512) {
    const int col = i & 63, kk = i >> 6;
    W1T[col * 8 + kk] = f2bf(W1[kk * 64 + col] * rs8);
  } else if (i < 4608) {
    const int ii = i - 512;
    const int k = ii >> 6, j = ii & 63;
    W2T[j * 64 + ((((k >> 3) ^ (j & 7)) << 3)) + (k & 7)] = f2bf(W2[ii] * 0.125f);
  } else if (i < 7680) {
    const int ii = i - 4608;
    const int k = ii / 48, j = ii % 48;
    const int jm = j % 3;
    const float s = (jm == 0) ? sc0 : ((jm == 1) ? sc1 : sc2);
    W3T[j * 64 + ((((k >> 3) ^ (j & 7)) << 3)) + (k & 7)] = f2bf(W3[ii] * 0.125f * s);
  }
}

// ===========================================================================
// precompute_C body (9 blocks, one d-slice each) -> CT[d][p][q pad 12]
// ===========================================================================
__device__ void precompute_body(
    int d, unsigned char* smem,
    const float* __restrict__ Ux_re, const float* __restrict__ Ux_im,
    const float* __restrict__ Uf_re, const float* __restrict__ Uf_im,
    const float* __restrict__ Vo_re, const float* __restrict__ Vo_im,
    float* __restrict__ CT) {
  float* G = (float*)smem;                // 2*729 f
  float* TL = (float*)(smem + 5840);      // 729 f
  float* cs9 = (float*)(smem + 8768);
  float* sn9 = (float*)(smem + 8816);
  const int t0 = threadIdx.x;

  if (t0 < 9) {
    float s, c;
    __sincosf(PI9 * (float)t0, &s, &c);
    cs9[t0] = c; sn9[t0] = s;
  }
  __syncthreads();

  for (int t = t0; t < 1458; t += 256) {
    const int which = t / 729, idx = t % 729;
    const int p = idx / 81, ab = idx % 81, a = ab / 9, b = ab % 9;
    const float* Ure = which ? Uf_re : Ux_re;
    const float* Uim = which ? Uf_im : Ux_im;
    float g = 0.f;
#pragma unroll
    for (int v = 0; v < 3; ++v) {
      const int uc = v + 2;
      float hre = 0.f, him = 0.f;
#pragma unroll
      for (int ui = 0; ui < 5; ++ui) {
        const int u = (ui + 7) % 9;
        const float re = Ure[p * 25 + ui * 5 + uc];
        const float im = Uim[p * 25 + ui * 5 + uc];
        const int k = (u * a) % 9;
        const float c = cs9[k], s = sn9[k];
        hre += re * c - im * s;
        him += re * s + im * c;
      }
      hre *= (1.f / 9.f); him *= (1.f / 9.f);
      if (v == 0) {
        g += hre;
      } else {
        const int k = (v * b) % 9;
        g += 2.f * (hre * cs9[k] - him * sn9[k]);
      }
    }
    G[which * 729 + p * 81 + ab] = g * (1.f / 9.f);
  }
  __syncthreads();

  for (int t = t0; t < 729; t += 256) {
    const int ab = t / 9, dd = t % 9, a = ab / 9, b = ab % 9;
    float acc = 0.f;
    for (int u = 0; u < 9; ++u)
      for (int v = 0; v < 5; ++v) {
        const int k = (u * a + v * b) % 9;
        acc += Vo_re[u * 45 + v * 9 + dd] * cs9[k]
             + Vo_im[u * 45 + v * 9 + dd] * sn9[k];
      }
    TL[ab * 9 + dd] = acc;
  }
  __syncthreads();

  if (t0 < 108) {
    const int p = t0 / 12, q = t0 % 12;
    float acc = 0.f;
    if (q < 9) {
      for (int ab = 0; ab < 81; ++ab)
        acc += G[p * 81 + ab] * G[729 + q * 81 + ab] * TL[ab * 9 + d];
    }
    CT[(d * 9 + p) * 12 + q] = acc;
  }
}

// ===========================================================================
// MLP body (2 reps = 128 edges/block); stage1 via MFMA; weights from global.
// ===========================================================================
__device__ void mlp_body(
    int mblk, unsigned char* smem, const float* __restrict__ win,
    const unsigned short* __restrict__ W1T,
    const unsigned short* __restrict__ W2T,
    const unsigned short* __restrict__ W3T,
    unsigned short* __restrict__ w48b) {
  unsigned short* H1 = (unsigned short*)smem + ((threadIdx.x >> 6) * 1024);
  unsigned short* H2 = (unsigned short*)(smem + 8192) + ((threadIdx.x >> 6) * 1024);
  const int t = threadIdx.x;
  const int w = t >> 6, l = t & 63;
  const int n16 = l & 15, g = l >> 4;
  const bool isg0 = (g == 0);

#pragma unroll 1
  for (int rep = 0; rep < 2; ++rep) {
    const int e = mblk * 128 + rep * 64 + w * 16 + n16;

    bf16x8 Aw;
#pragma unroll
    for (int j = 0; j < 8; ++j) Aw[j] = (__bf16)0.f;
    if (isg0) {
      const float4 A = *(const float4*)(win + (size_t)e * 8);
      const float4 B = *(const float4*)(win + (size_t)e * 8 + 4);
      Aw[0] = (__bf16)A.x; Aw[1] = (__bf16)A.y;
      Aw[2] = (__bf16)A.z; Aw[3] = (__bf16)A.w;
      Aw[4] = (__bf16)B.x; Aw[5] = (__bf16)B.y;
      Aw[6] = (__bf16)B.z; Aw[7] = (__bf16)B.w;
    }
#pragma unroll
    for (int nt = 0; nt < 4; ++nt) {
      const int col = nt * 16 + n16;
      us8 bz;
#pragma unroll
      for (int j = 0; j < 8; ++j) bz[j] = 0;
      const us8 bw = isg0 ? *(const us8*)&W1T[col * 8] : bz;
      f32x4 acc = {0.f, 0.f, 0.f, 0.f};
      acc = __builtin_amdgcn_mfma_f32_16x16x32_bf16(
          Aw, __builtin_bit_cast(bf16x8, bw), acc, 0, 0, 0);
#pragma unroll
      for (int r = 0; r < 4; ++r) {
        const int e2 = g * 4 + r;
        const int k2 = nt * 16 + n16;
        H1[e2 * 64 + ((((k2 >> 3) ^ (e2 & 7)) << 3)) + (k2 & 7)] =
            f2bf(ssp_f(acc[r]));
      }
    }
    __builtin_amdgcn_wave_barrier();

    {
      const us8 a0 = *(const us8*)&H1[n16 * 64 + ((g ^ (n16 & 7)) << 3)];
      const us8 a1 = *(const us8*)&H1[n16 * 64 + (((g + 4) ^ (n16 & 7)) << 3)];
      float hh[16];
#pragma unroll
      for (int nt = 0; nt < 4; ++nt) {
        const int j = nt * 16 + n16;
        const us8 b0 = *(const us8*)&W2T[j * 64 + ((g ^ (j & 7)) << 3)];
        const us8 b1 = *(const us8*)&W2T[j * 64 + (((g + 4) ^ (j & 7)) << 3)];
        f32x4 acc = {0.f, 0.f, 0.f, 0.f};
        acc = __builtin_amdgcn_mfma_f32_16x16x32_bf16(
            __builtin_bit_cast(bf16x8, a0), __builtin_bit_cast(bf16x8, b0), acc, 0, 0, 0);
        acc = __builtin_amdgcn_mfma_f32_16x16x32_bf16(
            __builtin_bit_cast(bf16x8, a1), __builtin_bit_cast(bf16x8, b1), acc, 0, 0, 0);
#pragma unroll
        for (int r = 0; r < 4; ++r) hh[nt * 4 + r] = ssp_f(acc[r]);
      }
#pragma unroll
      for (int nt = 0; nt < 4; ++nt)
#pragma unroll
        for (int r = 0; r < 4; ++r) {
          const int e2 = g * 4 + r;
          const int k2 = nt * 16 + n16;
          H2[e2 * 64 + ((((k2 >> 3) ^ (e2 & 7)) << 3)) + (k2 & 7)] =
              f2bf(hh[nt * 4 + r]);
        }
    }
    __builtin_amdgcn_wave_barrier();

    {
      const us8 c0 = *(const us8*)&H2[n16 * 64 + ((g ^ (n16 & 7)) << 3)];
      const us8 c1 = *(const us8*)&H2[n16 * 64 + (((g + 4) ^ (n16 & 7)) << 3)];
      const int ebase = mblk * 128 + rep * 64 + w * 16 + g * 4;
#pragma unroll
      for (int nt = 0; nt < 3; ++nt) {
        const int o = nt * 16 + n16;
        const int om = o / 3, ol = o - om * 3;
        const us8 b0 = *(const us8*)&W3T[o * 64 + ((g ^ (o & 7)) << 3)];
        const us8 b1 = *(const us8*)&W3T[o * 64 + (((g + 4) ^ (o & 7)) << 3)];
        f32x4 acc = {0.f, 0.f, 0.f, 0.f};
        acc = __builtin_amdgcn_mfma_f32_16x16x32_bf16(
            __builtin_bit_cast(bf16x8, c0), __builtin_bit_cast(bf16x8, b0), acc, 0, 0, 0);
        acc = __builtin_amdgcn_mfma_f32_16x16x32_bf16(
            __builtin_bit_cast(bf16x8, c1), __builtin_bit_cast(bf16x8, b1), acc, 0, 0, 0);
#pragma unroll
        for (int r = 0; r < 4; ++r)
          w48b[(size_t)(ebase + r) * 64 + ol * 16 + om] = f2bf(acc[r]);
      }
    }
    __builtin_amdgcn_wave_barrier();
  }
}

// ===========================================================================
// prep: [0,9) CT | [+nMlp) MLP | [+nScat) scatter(+filtS) | [+nXc) x->bf16
// Scatter also writes the dest-sorted bf16 filter row filtS[d*96+pos].
// ===========================================================================
__global__ __launch_bounds__(256) void prep_kernel(
    const float* __restrict__ win, const unsigned short* __restrict__ W1T,
    const unsigned short* __restrict__ W2T,
    const unsigned short* __restrict__ W3T,
    unsigned short* __restrict__ w48b,
    const int* __restrict__ dst, const int* __restrict__ src, int E,
    int* __restrict__ cnt, int2* __restrict__ slots2,
    const float* __restrict__ filt, unsigned short* __restrict__ filtS,
    const float* __restrict__ xsrc, int NR, unsigned short* __restrict__ xbf,
    const float* __restrict__ Ux_re, const float* __restrict__ Ux_im,
    const float* __restrict__ Uf_re, const float* __restrict__ Uf_im,
    const float* __restrict__ Vo_re, const float* __restrict__ Vo_im,
    float* __restrict__ CT, int nMlp, int nScat) {
  __shared__ __align__(16) unsigned char smem[16384];
  const int bid = blockIdx.x;
  if (bid < 9) {
    precompute_body(bid, smem, Ux_re, Ux_im, Uf_re, Uf_im, Vo_re, Vo_im, CT);
  } else if (bid < 9 + nMlp) {
    mlp_body(bid - 9, smem, win, W1T, W2T, W3T, w48b);
  } else if (bid < 9 + nMlp + nScat) {
    const int e = (bid - 9 - nMlp) * 256 + threadIdx.x;
    if (e < E) {
      const int d = dst[e];
      const int pos = atomicAdd(&cnt[d], 1);
      if (pos < 96) {
        const size_t idx = (size_t)d * 96 + pos;
        slots2[idx] = make_int2(e, src[e]);
        // dest-sorted bf16 filter row (coalesced read, scattered write)
        const float* fp = filt + (size_t)e * 9;
        unsigned int u0 = (unsigned)f2bf(fp[0]) | ((unsigned)f2bf(fp[1]) << 16);
        unsigned int u1 = (unsigned)f2bf(fp[2]) | ((unsigned)f2bf(fp[3]) << 16);
        unsigned int u2 = (unsigned)f2bf(fp[4]) | ((unsigned)f2bf(fp[5]) << 16);
        unsigned int u3 = (unsigned)f2bf(fp[6]) | ((unsigned)f2bf(fp[7]) << 16);
        unsigned int u4 = (unsigned)f2bf(fp[8]);
        unsigned short* op = filtS + idx * 12;
        *(uint2*)op = make_uint2(u0, u1);
        *(uint2*)(op + 4) = make_uint2(u2, u3);
        *(uint2*)(op + 8) = make_uint2(u4, 0u);
      }
    }
  } else {
    const int r = (bid - 9 - nMlp - nScat) * 256 + threadIdx.x;
    if (r < NR) {
      const float* xp = xsrc + (size_t)r * 9;
      unsigned int u0 = (unsigned)f2bf(xp[0]) | ((unsigned)f2bf(xp[1]) << 16);
      unsigned int u1 = (unsigned)f2bf(xp[2]) | ((unsigned)f2bf(xp[3]) << 16);
      unsigned int u2 = (unsigned)f2bf(xp[4]) | ((unsigned)f2bf(xp[5]) << 16);
      unsigned int u3 = (unsigned)f2bf(xp[6]) | ((unsigned)f2bf(xp[7]) << 16);
      unsigned int u4 = (unsigned)f2bf(xp[8]);
      unsigned short* op = xbf + (size_t)r * 12;
      *(uint2*)op = make_uint2(u0, u1);
      *(uint2*)(op + 4) = make_uint2(u2, u3);
      *(uint2*)(op + 8) = make_uint2(u4, 0u);
    }
  }
}

// ===========================================================================
// Node kernel: wave-per-node, fused Me, branch-free message MFMA + 4-FMA
// epilogue.  Af from dest-sorted filtS (coalesced, pre-bf16).
// ===========================================================================
__global__ __launch_bounds__(256) void node_kernel(
    const unsigned short* __restrict__ xbf,
    const unsigned short* __restrict__ filtS,
    const int* __restrict__ cnt, const int2* __restrict__ slots2,
    const unsigned short* __restrict__ w48b, const float* __restrict__ CT,
    float* __restrict__ out, int N) {
  __shared__ __align__(16) unsigned short meL[4][2304];  // il*144 + d*16 + p
  const int t = threadIdx.x, w = t >> 6, l = t & 63;
  const int n16 = l & 15, g = l >> 4;
  const int Ld = (n16 == 0) ? 0 : ((n16 < 4) ? 1 : 2);
  const bool dok = n16 < 9;
  const int drow = dok ? n16 : 0;
  const bool isg0 = (g == 0), isg1 = (g == 1);
  const int n = blockIdx.x * 4 + w;
  if (n >= N) return;

  int dT0, pT0, dT1, pT1, dT2, pT2, dT3, pT3, dT4, pT4, dT5, pT5;
  bool ok0, ok1, ok2, ok3, ok4, ok5;
  bf16x8 Bme0, Bme1, Bme2, Bme3, Bme4, Bme5;
#define MKB(tt, Bv, dv, pv, okv)                                             \
  {                                                                          \
    const int col = tt * 16 + n16;                                           \
    okv = (col < 81);                                                        \
    dv = okv ? col / 9 : 0;                                                  \
    pv = okv ? col % 9 : 0;                                                  \
    bf16x8 bv;                                                               \
    _Pragma("unroll")                                                        \
    for (int j = 0; j < 8; ++j) bv[j] = (__bf16)0.f;                         \
    if (okv) {                                                               \
      const float* cp = CT + col * 12;                                       \
      if (g == 0) {                                                          \
        const float4 ca = *(const float4*)cp;                                \
        const float4 cb = *(const float4*)(cp + 4);                          \
        bv[0] = (__bf16)ca.x; bv[1] = (__bf16)ca.y;                          \
        bv[2] = (__bf16)ca.z; bv[3] = (__bf16)ca.w;                          \
        bv[4] = (__bf16)cb.x; bv[5] = (__bf16)cb.y;                          \
        bv[6] = (__bf16)cb.z; bv[7] = (__bf16)cb.w;                          \
      } else if (g == 1) {                                                   \
        bv[0] = (__bf16)cp[8];                                               \
      }                                                                      \
    }                                                                        \
    Bv = bv;                                                                 \
  }
  MKB(0, Bme0, dT0, pT0, ok0); MKB(1, Bme1, dT1, pT1, ok1);
  MKB(2, Bme2, dT2, pT2, ok2); MKB(3, Bme3, dT3, pT3, ok3);
  MKB(4, Bme4, dT4, pT4, ok4); MKB(5, Bme5, dT5, pT5, ok5);
#undef MKB

  int deg = cnt[n];
  if (deg > 96) deg = 96;
  const int2* sl2 = slots2 + (size_t)n * 96;
  const unsigned short* flS = filtS + (size_t)n * 96 * 12;
  unsigned short* mlw = &meL[w][0];

  f32x4 accm = {0.f, 0.f, 0.f, 0.f};

  const int nb = (deg + 15) >> 4;
  for (int b = 0; b < nb; ++b) {
    const int base = b * 16;
    const int degb = (deg - base < 16) ? (deg - base) : 16;

    int esx = 0, esy = 0;
    if (n16 < degb) {
      const int2 v = sl2[base + n16];
      esx = v.x; esy = v.y;
    }
    // Af from dest-sorted bf16 filtS (coalesced 384B window per batch)
    bf16x8 Af;
#pragma unroll
    for (int j = 0; j < 8; ++j) Af[j] = (__bf16)0.f;
    if (n16 < degb) {
      const unsigned short* fp = flS + (size_t)(base + n16) * 12;
      if (g == 0) {
        const uint2 qa = *(const uint2*)fp;
        const uint2 qb = *(const uint2*)(fp + 4);
        u32x4 fv = {qa.x, qa.y, qb.x, qb.y};
        Af = __builtin_bit_cast(bf16x8, fv);
      } else if (g == 1) {
        const unsigned int q8 = *(const unsigned int*)(fp + 8);
        u32x4 fv = {q8 & 0xffffu, 0u, 0u, 0u};
        Af = __builtin_bit_cast(bf16x8, fv);
      }
    }

#define MEMFMA(Bv, dv, pv, okv)                                              \
    {                                                                        \
      f32x4 a6 = {0.f, 0.f, 0.f, 0.f};                                       \
      a6 = __builtin_amdgcn_mfma_f32_16x16x32_bf16(Af, Bv, a6, 0, 0, 0);     \
      if (okv) {                                                             \
        _Pragma("unroll")                                                    \
        for (int r = 0; r < 4; ++r)                                          \
          mlw[(g * 4 + r) * 144 + dv * 16 + pv] = f2bf(a6[r]);               \
      }                                                                      \
    }
    MEMFMA(Bme0, dT0, pT0, ok0); MEMFMA(Bme1, dT1, pT1, ok1);
    MEMFMA(Bme2, dT2, pT2, ok2); MEMFMA(Bme3, dT3, pT3, ok3);
    MEMFMA(Bme4, dT4, pT4, ok4); MEMFMA(Bme5, dT5, pT5, ok5);
#undef MEMFMA
    __builtin_amdgcn_wave_barrier();

    // ---- message loop with 2-deep A/B load pipeline
#define MSGLOAD(Q, QC, WV, il_)                                              \
    {                                                                        \
      const int e_ = __builtin_amdgcn_readlane(esx, (il_));                  \
      const int s_ = __builtin_amdgcn_readlane(esy, (il_));                  \
      const unsigned short* xrp_ = xbf + (size_t)s_ * 192 + n16 * 12;        \
      Q = *(const u32x4*)xrp_;                                               \
      QC = *(const unsigned int*)(xrp_ + 8);                                 \
      WV = *(const uint2*)(w48b + (size_t)e_ * 64 + Ld * 16 + g * 4);        \
    }

    u32x4 qA, qB;
    unsigned int qcA, qcB;
    uint2 wvA, wvB;
    MSGLOAD(qA, qcA, wvA, 0);
    if (degb > 1) MSGLOAD(qB, qcB, wvB, 1);

#pragma unroll 1
    for (int il = 0; il < degb; ++il) {
      const u32x4 q = qA;
      const unsigned int qc = qcA;
      const uint2 wv = wvA;
      // rotate pipeline
      qA = qB; qcA = qcB; wvA = wvB;
      if (il + 2 < degb) MSGLOAD(qB, qcB, wvB, il + 2);

      const unsigned short* mr = mlw + il * 144 + drow * 16;
      const u32x4 mdv = *(const u32x4*)mr;
      const unsigned int md4 = (*(const unsigned int*)(mr + 8)) & 0xffffu;

      u32x4 av;
      av[0] = isg0 ? q[0] : (isg1 ? qc : 0u);
      av[1] = isg0 ? q[1] : 0u;
      av[2] = isg0 ? q[2] : 0u;
      av[3] = isg0 ? q[3] : 0u;
      u32x4 bv;
      bv[0] = isg0 ? mdv[0] : (isg1 ? md4 : 0u);
      bv[1] = isg0 ? mdv[1] : 0u;
      bv[2] = isg0 ? mdv[2] : 0u;
      bv[3] = isg0 ? mdv[3] : 0u;

      f32x4 c1 = {0.f, 0.f, 0.f, 0.f};
      c1 = __builtin_amdgcn_mfma_f32_16x16x32_bf16(
          __builtin_bit_cast(bf16x8, av), __builtin_bit_cast(bf16x8, bv),
          c1, 0, 0, 0);
      accm[0] = fmaf(c1[0], bfLO(wv.x), accm[0]);
      accm[1] = fmaf(c1[1], bfHI(wv.x), accm[1]);
      accm[2] = fmaf(c1[2], bfLO(wv.y), accm[2]);
      accm[3] = fmaf(c1[3], bfHI(wv.y), accm[3]);
    }
#undef MSGLOAD
    __builtin_amdgcn_wave_barrier();
  }

  if (dok) {
    float* op = out + (size_t)n * 144 + (g * 4) * 9 + n16;
    op[0]  = accm[0];
    op[9]  = accm[1];
    op[18] = accm[2];
    op[27] = accm[3];
  }
}

// ---------------------------------------------------------------------------
extern "C" void kernel_launch(void* const* d_in, const int* in_sizes, int n_in,
                              void* d_out, int out_size, void* d_ws, size_t ws_size,
                              hipStream_t stream) {
  const float* x      = (const float*)d_in[0];
  const float* filt   = (const float*)d_in[1];
  const float* win    = (const float*)d_in[2];
  const int*   eidx   = (const int*)d_in[3];
  const float* Ux_re  = (const float*)d_in[4];
  const float* Ux_im  = (const float*)d_in[5];
  const float* Uf_re  = (const float*)d_in[6];
  const float* Uf_im  = (const float*)d_in[7];
  const float* Vo_re  = (const float*)d_in[8];
  const float* Vo_im  = (const float*)d_in[9];
  const float* W1     = (const float*)d_in[10];
  const float* W2     = (const float*)d_in[11];
  const float* W3     = (const float*)d_in[12];
  const float* a_w    = (const float*)d_in[13];
  const float* den    = (const float*)d_in[14];
  float* out = (float*)d_out;

  const int N = in_sizes[0] / 144;          // 10000
  const int E = in_sizes[3] / 2;            // 160000
  const int NR = N * 16;                    // x rows (node, m)
  const int* dst = eidx;
  const int* src = eidx + E;

  char* wsb = (char*)d_ws;
  const size_t off_cnt  = 8192;
  const size_t off_slot = off_cnt + 40960;
  const size_t off_w48  = off_slot + (size_t)N * 96 * 8;
  const size_t off_xbf  = off_w48 + (size_t)E * 64 * 2;
  const size_t off_w1t  = off_xbf + (size_t)NR * 12 * 2;
  const size_t off_w2t  = off_w1t + 512 * 2;
  const size_t off_w3t  = off_w2t + 4096 * 2;
  const size_t off_flS  = off_w3t + 3072 * 2 + 1024;

  float*          CT    = (float*)wsb;
  int*            cnt   = (int*)(wsb + off_cnt);
  int2*           slot2 = (int2*)(wsb + off_slot);
  unsigned short* w48b  = (unsigned short*)(wsb + off_w48);  // E*64 shorts
  unsigned short* xbf   = (unsigned short*)(wsb + off_xbf);  // NR*12 shorts
  unsigned short* W1T   = (unsigned short*)(wsb + off_w1t);
  unsigned short* W2T   = (unsigned short*)(wsb + off_w2t);
  unsigned short* W3T   = (unsigned short*)(wsb + off_w3t);
  unsigned short* filtS = (unsigned short*)(wsb + off_flS);  // N*96*12 shorts

  const int nMlp  = E / 128;                // 1250
  const int nScat = (E + 255) / 256;        // 625
  const int nXc   = (NR + 255) / 256;       // 625

  wconv_kernel<<<(N + 255) / 256, 256, 0, stream>>>(
      W1, W2, W3, a_w, den, W1T, W2T, W3T, cnt, N);
  prep_kernel<<<9 + nMlp + nScat + nXc, 256, 0, stream>>>(
      win, W1T, W2T, W3T, w48b,
      dst, src, E, cnt, slot2,
      filt, filtS,
      x, NR, xbf,
      Ux_re, Ux_im, Uf_re, Uf_im, Vo_re, Vo_im, CT, nMlp, nScat);
  node_kernel<<<(N + 3) / 4, 256, 0, stream>>>(
      xbf, filtS, cnt, slot2, w48b, CT, out, N);
}